// Round 2
// baseline (133.746 us; speedup 1.0000x reference)
//
#include <hip/hip_runtime.h>

// Undistort (inverse radial distortion resample), C=3, H=W=2048, fp32.
// rd*cos(theta) == xur/(1-k*ru^2), rd*sin(theta) == yur/(1-k*ru^2):
// the coordinate map is FMAs + one fast reciprocal (no sqrt/atan2/sincos).
//
// Round-1 structure: 4 px/thread along x (float4 stores), 2D tiles of
// 128x8 px per 256-thread block, bijective XCD-aware block swizzle
// (4096 tiles % 8 == 0), coordinates computed once and reused for all
// 3 channels; 16 independent gather loads in flight per channel round.

#define UND_C 3
#define UND_H 2048
#define UND_W 2048
#define TILE_W 128   // 32 threads * 4 px
#define TILE_H 8
#define PLANE (UND_H * UND_W)

__global__ __launch_bounds__(256, 2) void undistort_kernel(
    const float* __restrict__ im,   // [C][H][W]
    const float* __restrict__ kp,
    const float* __restrict__ dxp,
    const float* __restrict__ dyp,
    float* __restrict__ out)        // [C][H][W]
{
    constexpr int W = UND_W, H = UND_H;
    constexpr int TPX = 16;                 // tiles per tile-row: 2048/128
    constexpr int NWG = (W / TILE_W) * (H / TILE_H);  // 4096
    constexpr int PER_XCD = NWG / 8;        // 512, NWG % 8 == 0 -> bijective

    // XCD-aware swizzle: each XCD owns a contiguous horizontal slab.
    const int b  = blockIdx.x;
    const int bs = (b & 7) * PER_XCD + (b >> 3);
    const int bx = bs & (TPX - 1);
    const int by = bs / TPX;

    const int tid = threadIdx.x;
    const int lx  = tid & 31;               // 32 threads across tile width
    const int ly  = tid >> 5;               // 8 rows
    const int x0  = bx * TILE_W + lx * 4;
    const int y   = by * TILE_H + ly;

    const float k  = kp[0];
    const float dx = dxp[0];
    const float dy = dyp[0];

    const float yur = ((float)y - dy) * (1.0f / (float)H) - 0.5f;
    const float yur2 = yur * yur;

    float w00[4], w01[4], w10[4], w11[4];
    int   o00[4], o01[4], o10[4], o11[4];
    bool  valid[4];

#pragma unroll
    for (int j = 0; j < 4; ++j) {
        const float xur = ((float)(x0 + j) - dx) * (1.0f / (float)W) - 0.5f;
        const float r2  = xur * xur + yur2;
        const float s   = __builtin_amdgcn_rcpf(1.0f - k * r2);  // rd/ru

        const float xd = (xur * s + 0.5f) * (float)W + dx;
        const float yd = (yur * s + 0.5f) * (float)H + dy;

        const float xf = floorf(xd);
        const float yf = floorf(yd);
        const float xc = ceilf(xd);
        const float yc = ceilf(yd);

        const float ox  = xd - xf;
        const float oy  = yd - yf;
        const float onx = 1.0f - ox;
        const float ony = 1.0f - oy;

        valid[j] = (xf >= 0.0f) & (xc < (float)W) & (yf >= 0.0f) & (yc < (float)H);

        int xfi = (int)xf; xfi = xfi < 0 ? 0 : (xfi > W - 1 ? W - 1 : xfi);
        int xci = (int)xc; xci = xci < 0 ? 0 : (xci > W - 1 ? W - 1 : xci);
        int yfi = (int)yf; yfi = yfi < 0 ? 0 : (yfi > H - 1 ? H - 1 : yfi);
        int yci = (int)yc; yci = yci < 0 ? 0 : (yci > H - 1 ? H - 1 : yci);

        const int rowf = yfi * W;
        const int rowc = yci * W;
        o00[j] = rowf + xfi;
        o01[j] = rowf + xci;
        o10[j] = rowc + xfi;
        o11[j] = rowc + xci;

        w00[j] = onx * ony;
        w01[j] = ox * ony;
        w10[j] = onx * oy;
        w11[j] = ox * oy;
    }

    const int outoff = y * W + x0;

#pragma unroll
    for (int c = 0; c < UND_C; ++c) {
        const float* __restrict__ p = im + (size_t)c * PLANE;
        float v00[4], v01[4], v10[4], v11[4];
        // 16 independent loads issued back-to-back per channel.
#pragma unroll
        for (int j = 0; j < 4; ++j) v00[j] = p[o00[j]];
#pragma unroll
        for (int j = 0; j < 4; ++j) v01[j] = p[o01[j]];
#pragma unroll
        for (int j = 0; j < 4; ++j) v10[j] = p[o10[j]];
#pragma unroll
        for (int j = 0; j < 4; ++j) v11[j] = p[o11[j]];

        float4 r;
        float* rr = (float*)&r;
#pragma unroll
        for (int j = 0; j < 4; ++j) {
            float acc = w00[j] * v00[j] + w01[j] * v01[j]
                      + w10[j] * v10[j] + w11[j] * v11[j];
            rr[j] = valid[j] ? acc : 0.0f;
        }
        *(float4*)(out + (size_t)c * PLANE + outoff) = r;
    }
}

extern "C" void kernel_launch(void* const* d_in, const int* in_sizes, int n_in,
                              void* d_out, int out_size, void* d_ws, size_t ws_size,
                              hipStream_t stream) {
    (void)in_sizes; (void)n_in; (void)d_ws; (void)ws_size; (void)out_size;
    const float* im = (const float*)d_in[0];
    const float* k  = (const float*)d_in[1];
    const float* dx = (const float*)d_in[2];
    const float* dy = (const float*)d_in[3];
    float* out = (float*)d_out;

    constexpr int NWG = (UND_W / TILE_W) * (UND_H / TILE_H);  // 4096
    undistort_kernel<<<NWG, 256, 0, stream>>>(im, k, dx, dy, out);
}

// Round 4
// 120.798 us; speedup vs baseline: 1.1072x; 1.1072x over previous
//
#include <hip/hip_runtime.h>

// Undistort (inverse radial distortion resample), C=3, H=W=2048, fp32.
// rd*cos(theta) == xur/(1-k*ru^2), rd*sin(theta) == yur/(1-k*ru^2):
// coordinate map = FMAs + one fast reciprocal (no sqrt/atan2/sincos).
//
// Round-2 structure: lane-consecutive x layout. A wave covers 256
// consecutive x (lane i -> x0+i, 4 px/thread strided by 64), so every
// gather instruction's 64 lanes are ~4B apart -> ~4-6 cache lines per
// instruction instead of 16 (the round-1 limiter). Block = 4 waves
// stacked in y: tile 256x4. Bijective XCD swizzle over 4096 tiles.
// ceil() replaced by xfi+1 (weight ox=0 makes the extra tap a no-op;
// validity check is xd <= W-1 exactly as ceil(xd) < W).

#define UND_C 3
#define UND_H 2048
#define UND_W 2048
#define PLANE (UND_H * UND_W)

__global__ __launch_bounds__(256, 4) void undistort_kernel(
    const float* __restrict__ im,   // [C][H][W]
    const float* __restrict__ kp,
    const float* __restrict__ dxp,
    const float* __restrict__ dyp,
    float* __restrict__ out)        // [C][H][W]
{
    constexpr int W = UND_W, H = UND_H;
    constexpr int TPX = 8;                   // x-tiles per row: 2048/256
    constexpr int NWG = TPX * (H / 4);       // 4096
    constexpr int PER_XCD = NWG / 8;         // 512 (NWG % 8 == 0 -> bijective)

    // XCD-aware swizzle: each XCD owns a contiguous y-slab of tiles.
    const int b  = blockIdx.x;
    const int bs = (b & 7) * PER_XCD + (b >> 3);
    const int bx = bs & (TPX - 1);
    const int by = bs >> 3;

    const int lane = threadIdx.x & 63;
    const int wid  = threadIdx.x >> 6;
    const int x0   = bx * 256 + lane;        // lane-consecutive x
    const int y    = by * 4 + wid;

    const float k  = kp[0];
    const float dx = dxp[0];
    const float dy = dyp[0];

    const float yur  = ((float)y - dy) * (1.0f / (float)H) - 0.5f;
    const float yur2 = yur * yur;

    float w00[4], w01[4], w10[4], w11[4];
    int   o00[4], o01[4], o10[4], o11[4];
    bool  valid[4];

#pragma unroll
    for (int j = 0; j < 4; ++j) {
        const int   x   = x0 + 64 * j;
        const float xur = ((float)x - dx) * (1.0f / (float)W) - 0.5f;
        const float r2  = xur * xur + yur2;
        const float s   = __builtin_amdgcn_rcpf(1.0f - k * r2);  // rd/ru

        const float xd = (xur * s + 0.5f) * (float)W + dx;
        const float yd = (yur * s + 0.5f) * (float)H + dy;

        const float xf = floorf(xd);
        const float yf = floorf(yd);

        const float ox  = xd - xf;
        const float oy  = yd - yf;
        const float onx = 1.0f - ox;
        const float ony = 1.0f - oy;

        // ceil(xd) < W  <=>  xd <= W-1 ; likewise for y.
        valid[j] = (xf >= 0.0f) & (xd <= (float)(W - 1)) &
                   (yf >= 0.0f) & (yd <= (float)(H - 1));

        int xfi = (int)xf; xfi = xfi < 0 ? 0 : (xfi > W - 1 ? W - 1 : xfi);
        int yfi = (int)yf; yfi = yfi < 0 ? 0 : (yfi > H - 1 ? H - 1 : yfi);
        const int xci = xfi + 1 > W - 1 ? W - 1 : xfi + 1;
        const int yci = yfi + 1 > H - 1 ? H - 1 : yfi + 1;

        const int rowf = yfi * W;
        const int rowc = yci * W;
        o00[j] = rowf + xfi;
        o01[j] = rowf + xci;
        o10[j] = rowc + xfi;
        o11[j] = rowc + xci;

        w00[j] = onx * ony;
        w01[j] = ox * ony;
        w10[j] = onx * oy;
        w11[j] = ox * oy;
    }

    const int outoff = y * W + x0;

#pragma unroll
    for (int c = 0; c < UND_C; ++c) {
        const float* __restrict__ p = im + (size_t)c * PLANE;
        float v00[4], v01[4], v10[4], v11[4];
#pragma unroll
        for (int j = 0; j < 4; ++j) v00[j] = p[o00[j]];
#pragma unroll
        for (int j = 0; j < 4; ++j) v01[j] = p[o01[j]];
#pragma unroll
        for (int j = 0; j < 4; ++j) v10[j] = p[o10[j]];
#pragma unroll
        for (int j = 0; j < 4; ++j) v11[j] = p[o11[j]];

        float* __restrict__ po = out + (size_t)c * PLANE + outoff;
#pragma unroll
        for (int j = 0; j < 4; ++j) {
            float acc = w00[j] * v00[j] + w01[j] * v01[j]
                      + w10[j] * v10[j] + w11[j] * v11[j];
            po[64 * j] = valid[j] ? acc : 0.0f;
        }
    }
}

extern "C" void kernel_launch(void* const* d_in, const int* in_sizes, int n_in,
                              void* d_out, int out_size, void* d_ws, size_t ws_size,
                              hipStream_t stream) {
    (void)in_sizes; (void)n_in; (void)d_ws; (void)ws_size; (void)out_size;
    const float* im = (const float*)d_in[0];
    const float* k  = (const float*)d_in[1];
    const float* dx = (const float*)d_in[2];
    const float* dy = (const float*)d_in[3];
    float* out = (float*)d_out;

    constexpr int NWG = 8 * (UND_H / 4);  // 4096
    undistort_kernel<<<NWG, 256, 0, stream>>>(im, k, dx, dy, out);
}

// Round 6
// 120.448 us; speedup vs baseline: 1.1104x; 1.0029x over previous
//
#include <hip/hip_runtime.h>

// Undistort (inverse radial distortion resample), C=3, H=W=2048, fp32.
// rd*cos(theta) == xur/(1-k*ru^2), rd*sin(theta) == yur/(1-k*ru^2):
// coordinate map = FMAs + one fast reciprocal (no sqrt/atan2/sincos).
//
// Round-4 structure: channel-split grid (channels share no cache lines,
// so splitting is free locality-wise) -> 12288 blocks, 3x the waves for
// latency hiding. Each thread: 4 px along x (lane-consecutive wave span
// of 256 x), ALL 16 gather addresses computed first, ALL 16 gathers
// issued back-to-back, then all FMAs — one deep VMEM batch per thread
// instead of 4-load trickles. Nontemporal stores keep the write stream
// out of L2 so the input stays resident. Bijective XCD swizzle.

#define UND_C 3
#define UND_H 2048
#define UND_W 2048
#define PLANE (UND_H * UND_W)

__global__ __launch_bounds__(256, 4) void undistort_kernel(
    const float* __restrict__ im,   // [C][H][W]
    const float* __restrict__ kp,
    const float* __restrict__ dxp,
    const float* __restrict__ dyp,
    float* __restrict__ out)        // [C][H][W]
{
    constexpr int W = UND_W, H = UND_H;
    constexpr int NWG = UND_C * 8 * (H / 4);   // 12288
    constexpr int PER_XCD = NWG / 8;           // 1536 (bijective: NWG%8==0)

    // XCD-aware swizzle: each XCD owns a contiguous chunk of (ch,tile) space.
    const int b  = blockIdx.x;
    const int bs = (b & 7) * PER_XCD + (b >> 3);
    const int ch = bs >> 12;          // /4096 tiles per channel
    const int t  = bs & 4095;
    const int bx = t & 7;             // 8 x-tiles of 256 px
    const int by = t >> 3;            // 512 y-tiles of 4 rows

    const int lane = threadIdx.x & 63;
    const int wid  = threadIdx.x >> 6;
    const int x0   = bx * 256 + lane;          // lane-consecutive x
    const int y    = by * 4 + wid;

    const float k  = kp[0];
    const float dx = dxp[0];
    const float dy = dyp[0];

    const float yur  = ((float)y - dy) * (1.0f / (float)H) - 0.5f;
    const float yur2 = yur * yur;

    float wgt[16];
    int   off[16];
    bool  valid[4];

#pragma unroll
    for (int j = 0; j < 4; ++j) {
        const int   x   = x0 + 64 * j;
        const float xur = ((float)x - dx) * (1.0f / (float)W) - 0.5f;
        const float r2  = xur * xur + yur2;
        const float s   = __builtin_amdgcn_rcpf(1.0f - k * r2);  // rd/ru

        const float xd = (xur * s + 0.5f) * (float)W + dx;
        const float yd = (yur * s + 0.5f) * (float)H + dy;

        const float xf = floorf(xd);
        const float yf = floorf(yd);

        const float ox  = xd - xf;
        const float oy  = yd - yf;
        const float onx = 1.0f - ox;
        const float ony = 1.0f - oy;

        // ceil(xd) < W  <=>  xd <= W-1 ; likewise for y.
        valid[j] = (xf >= 0.0f) & (xd <= (float)(W - 1)) &
                   (yf >= 0.0f) & (yd <= (float)(H - 1));

        int xfi = (int)xf; xfi = xfi < 0 ? 0 : (xfi > W - 1 ? W - 1 : xfi);
        int yfi = (int)yf; yfi = yfi < 0 ? 0 : (yfi > H - 1 ? H - 1 : yfi);
        const int xci = xfi + 1 > W - 1 ? W - 1 : xfi + 1;
        const int yci = yfi + 1 > H - 1 ? H - 1 : yfi + 1;

        const int rowf = yfi * W;
        const int rowc = yci * W;
        off[j * 4 + 0] = rowf + xfi;
        off[j * 4 + 1] = rowf + xci;
        off[j * 4 + 2] = rowc + xfi;
        off[j * 4 + 3] = rowc + xci;

        wgt[j * 4 + 0] = onx * ony;
        wgt[j * 4 + 1] = ox * ony;
        wgt[j * 4 + 2] = onx * oy;
        wgt[j * 4 + 3] = ox * oy;
    }

    const float* __restrict__ p = im + (size_t)ch * PLANE;

    // One deep batch: 16 independent gathers in flight.
    float v[16];
#pragma unroll
    for (int i = 0; i < 16; ++i) v[i] = p[off[i]];

    float* __restrict__ po = out + (size_t)ch * PLANE + y * W + x0;
#pragma unroll
    for (int j = 0; j < 4; ++j) {
        float acc = wgt[j * 4 + 0] * v[j * 4 + 0] + wgt[j * 4 + 1] * v[j * 4 + 1]
                  + wgt[j * 4 + 2] * v[j * 4 + 2] + wgt[j * 4 + 3] * v[j * 4 + 3];
        __builtin_nontemporal_store(valid[j] ? acc : 0.0f, po + 64 * j);
    }
}

extern "C" void kernel_launch(void* const* d_in, const int* in_sizes, int n_in,
                              void* d_out, int out_size, void* d_ws, size_t ws_size,
                              hipStream_t stream) {
    (void)in_sizes; (void)n_in; (void)d_ws; (void)ws_size; (void)out_size;
    const float* im = (const float*)d_in[0];
    const float* k  = (const float*)d_in[1];
    const float* dx = (const float*)d_in[2];
    const float* dy = (const float*)d_in[3];
    float* out = (float*)d_out;

    constexpr int NWG = UND_C * 8 * (UND_H / 4);  // 12288
    undistort_kernel<<<NWG, 256, 0, stream>>>(im, k, dx, dy, out);
}

// Round 10
// 117.109 us; speedup vs baseline: 1.1421x; 1.0285x over previous
//
#include <hip/hip_runtime.h>

// Undistort (inverse radial distortion resample), C=3, H=W=2048, fp32.
// rd*cos(theta) == xur/(1-k*ru^2), rd*sin(theta) == yur/(1-k*ru^2):
// coordinate map = FMAs + one fast reciprocal (no sqrt/atan2/sincos).
//
// Round-6 structure: channel-split grid (12288 blocks), lane-consecutive
// x (wave spans 256 consecutive x, 4 px/thread strided by 64), deep
// VMEM batches, nontemporal stores, bijective XCD swizzle.
//
// Round-6 finding: time tracks total VMEM wave-instruction count
// (~26-32 cyc/instr address processing), not lines/BW/occupancy.
// Round-7 lever: paired-tap gathers. The two x-taps of each row are
// adjacent, so one unaligned 8B load (global_load_dwordx2, gfx950
// unaligned mode; memcpy fallback-safe) replaces two dword gathers:
// 20 -> 12 VMEM instrs per thread. Edge: pair base clamped to
// [0, W-2]; xfi>=W-1 selects pair.y for tap0 (tap1 weight is 0 there,
// or the output is invalid-masked), so pairs never cross a row end.

#define UND_C 3
#define UND_H 2048
#define UND_W 2048
#define PLANE (UND_H * UND_W)

__device__ __forceinline__ float2 ld2(const float* __restrict__ a) {
    float2 r;
    __builtin_memcpy(&r, a, 8);   // align-4 8B load -> global_load_dwordx2
    return r;
}

__global__ __launch_bounds__(256, 4) void undistort_kernel(
    const float* __restrict__ im,   // [C][H][W]
    const float* __restrict__ kp,
    const float* __restrict__ dxp,
    const float* __restrict__ dyp,
    float* __restrict__ out)        // [C][H][W]
{
    constexpr int W = UND_W, H = UND_H;
    constexpr int NWG = UND_C * 8 * (H / 4);   // 12288
    constexpr int PER_XCD = NWG / 8;           // 1536 (bijective: NWG%8==0)

    // XCD-aware swizzle: each XCD owns a contiguous chunk of (ch,tile) space.
    const int b  = blockIdx.x;
    const int bs = (b & 7) * PER_XCD + (b >> 3);
    const int ch = bs >> 12;          // /4096 tiles per channel
    const int t  = bs & 4095;
    const int bx = t & 7;             // 8 x-tiles of 256 px
    const int by = t >> 3;            // 512 y-tiles of 4 rows

    const int lane = threadIdx.x & 63;
    const int wid  = threadIdx.x >> 6;
    const int x0   = bx * 256 + lane;          // lane-consecutive x
    const int y    = by * 4 + wid;

    const float k  = kp[0];
    const float dx = dxp[0];
    const float dy = dyp[0];

    const float yur  = ((float)y - dy) * (1.0f / (float)H) - 0.5f;
    const float yur2 = yur * yur;

    float w00[4], w01[4], w10[4], w11[4];
    int   offf[4], offc[4];
    bool  hi[4], valid[4];

#pragma unroll
    for (int j = 0; j < 4; ++j) {
        const int   x   = x0 + 64 * j;
        const float xur = ((float)x - dx) * (1.0f / (float)W) - 0.5f;
        const float r2  = xur * xur + yur2;
        const float s   = __builtin_amdgcn_rcpf(1.0f - k * r2);  // rd/ru

        const float xd = (xur * s + 0.5f) * (float)W + dx;
        const float yd = (yur * s + 0.5f) * (float)H + dy;

        const float xf = floorf(xd);
        const float yf = floorf(yd);

        const float ox  = xd - xf;
        const float oy  = yd - yf;
        const float onx = 1.0f - ox;
        const float ony = 1.0f - oy;

        // ceil(xd) < W  <=>  xd <= W-1 ; likewise for y.
        valid[j] = (xf >= 0.0f) & (xd <= (float)(W - 1)) &
                   (yf >= 0.0f) & (yd <= (float)(H - 1));

        int xfi = (int)xf;
        int yfi = (int)yf; yfi = yfi < 0 ? 0 : (yfi > H - 1 ? H - 1 : yfi);
        const int yci = yfi + 1 > H - 1 ? H - 1 : yfi + 1;

        hi[j] = xfi >= W - 1;                       // tap0 = pair.y there
        int xp = xfi < 0 ? 0 : (xfi > W - 2 ? W - 2 : xfi);  // pair base

        offf[j] = yfi * W + xp;
        offc[j] = yci * W + xp;

        w00[j] = onx * ony;
        w01[j] = ox * ony;
        w10[j] = onx * oy;
        w11[j] = ox * oy;
    }

    const float* __restrict__ p = im + (size_t)ch * PLANE;

    // 8 independent paired-tap gathers in flight.
    float2 vf[4], vc[4];
#pragma unroll
    for (int j = 0; j < 4; ++j) vf[j] = ld2(p + offf[j]);
#pragma unroll
    for (int j = 0; j < 4; ++j) vc[j] = ld2(p + offc[j]);

    float* __restrict__ po = out + (size_t)ch * PLANE + y * W + x0;
#pragma unroll
    for (int j = 0; j < 4; ++j) {
        const float v00 = hi[j] ? vf[j].y : vf[j].x;
        const float v10 = hi[j] ? vc[j].y : vc[j].x;
        float acc = w00[j] * v00 + w01[j] * vf[j].y
                  + w10[j] * v10 + w11[j] * vc[j].y;
        __builtin_nontemporal_store(valid[j] ? acc : 0.0f, po + 64 * j);
    }
}

extern "C" void kernel_launch(void* const* d_in, const int* in_sizes, int n_in,
                              void* d_out, int out_size, void* d_ws, size_t ws_size,
                              hipStream_t stream) {
    (void)in_sizes; (void)n_in; (void)d_ws; (void)ws_size; (void)out_size;
    const float* im = (const float*)d_in[0];
    const float* k  = (const float*)d_in[1];
    const float* dx = (const float*)d_in[2];
    const float* dy = (const float*)d_in[3];
    float* out = (float*)d_out;

    constexpr int NWG = UND_C * 8 * (UND_H / 4);  // 12288
    undistort_kernel<<<NWG, 256, 0, stream>>>(im, k, dx, dy, out);
}